// Round 2
// baseline (958.539 us; speedup 1.0000x reference)
//
#include <hip/hip_runtime.h>
#include <cstdint>
#include <cstddef>

#define NNODES   4096        // B
#define DIM      256         // D
#define NPAIRS   8128        // 128*127/2
#define NPAD     8192        // padded pair columns
#define NEDGE_IN 131072      // E
#define M_EDGES  (NEDGE_IN + NNODES)
#define NEG_SLOPE 0.2f
#define EPS_G     1e-10f
#define KSTEPS   12          // 768 / 64
#define MARGIN   1e-3f       // |dlt-thr| below this -> exact fp32 recompute

#define AS3(p) ((__attribute__((address_space(3))) void*)(p))
#define AS1(p) ((const __attribute__((address_space(1))) void*)(p))

typedef __attribute__((ext_vector_type(8))) short bf16x8;   // 8 bf16 = 4 VGPR
typedef __attribute__((ext_vector_type(4))) float f32x4;

// round-to-nearest-even fp32 -> bf16 (bit math, deterministic)
__device__ __forceinline__ unsigned short f2bf(float f) {
  unsigned u = __float_as_uint(f);
  unsigned r = u + 0x7fffu + ((u >> 16) & 1u);
  return (unsigned short)(r >> 16);
}
__device__ __forceinline__ float bf2f(unsigned short h) {
  return __uint_as_float(((unsigned)h) << 16);
}

// ---------------- CSR build ----------------
__global__ void k_deg(const int* __restrict__ ei, int* __restrict__ deg) {
  int e = blockIdx.x * 256 + threadIdx.x;
  if (e >= M_EDGES) return;
  int dst = (e < NEDGE_IN) ? ei[NEDGE_IN + e] : (e - NEDGE_IN);
  atomicAdd(&deg[dst], 1);
}

__global__ void k_scan(const int* __restrict__ deg, int* __restrict__ offs,
                       int* __restrict__ cursor) {
  __shared__ int lds[1024];
  int t = threadIdx.x;
  int4 d = *(const int4*)&deg[t * 4];
  int s = d.x + d.y + d.z + d.w;
  lds[t] = s;
  __syncthreads();
  for (int off = 1; off < 1024; off <<= 1) {
    int v = 0;
    if (t >= off) v = lds[t - off];
    __syncthreads();
    if (t >= off) lds[t] += v;
    __syncthreads();
  }
  int base = lds[t] - s;               // exclusive prefix
  int o0 = base, o1 = o0 + d.x, o2 = o1 + d.y, o3 = o2 + d.z;
  offs[t*4+0] = o0; offs[t*4+1] = o1; offs[t*4+2] = o2; offs[t*4+3] = o3;
  cursor[t*4+0] = o0; cursor[t*4+1] = o1; cursor[t*4+2] = o2; cursor[t*4+3] = o3;
  if (t == 1023) offs[4096] = lds[1023];
}

__global__ void k_scatter(const int* __restrict__ ei, int* __restrict__ cursor,
                          int* __restrict__ srcs) {
  int e = blockIdx.x * 256 + threadIdx.x;
  if (e >= M_EDGES) return;
  int src, dst;
  if (e < NEDGE_IN) { src = ei[e]; dst = ei[NEDGE_IN + e]; }
  else              { src = dst = e - NEDGE_IN; }
  int pos = atomicAdd(&cursor[dst], 1);
  srcs[pos] = src;
}

// ------- W prep: fcW (k-major) -> Wdn (f32 n-major [NPAD][256]),
//   B2p packed bf16 tiles [nt][ks][128][64] pre-swizzled (slot ^= row&7), cdf.
//   K-step order: ks 0..3 = hi, 4..7 = lo, 8..11 = hi  (B' = [hi|lo|hi]) -------
__global__ __launch_bounds__(256) void k_wprep(const float* __restrict__ fcW,
                                               const float* __restrict__ fcb,
                                               float* __restrict__ Wdn,
                                               unsigned short* __restrict__ B2p,
                                               float* __restrict__ cdf) {
  __shared__ float t[64][65];
  int n0 = blockIdx.x * 64;    // 0..8128 step 64
  int k0 = blockIdx.y * 64;    // 0..192  step 64
  for (int i = threadIdx.x; i < 4096; i += 256) {
    int r = i >> 6, c = i & 63;
    int n = n0 + c;
    float d = 0.f;
    if (n < NPAIRS) {
      const float* p = fcW + (size_t)(k0 + r) * (2 * NPAIRS) + 2 * n;
      d = p[0] - p[1];
    }
    t[r][c] = d;
  }
  __syncthreads();
  int ksb = k0 >> 6;           // 0..3
  for (int i = threadIdx.x; i < 4096; i += 256) {
    int rn = i >> 6, ck = i & 63;
    int n = n0 + rn, k = k0 + ck;
    float d = t[ck][rn];
    Wdn[(size_t)n * DIM + k] = d;
    unsigned short hi = f2bf(d);
    unsigned short lo = f2bf(d - bf2f(hi));
    int nt = n >> 7, nn = n & 127;
    int s = ck >> 3, e = ck & 7;
    int ss = s ^ (nn & 7);
    size_t ib = ((size_t)nn << 6) + (ss << 3) + e;
    size_t tb = (size_t)nt * KSTEPS;
    B2p[((tb + ksb)     << 13) + ib] = hi;
    B2p[((tb + 4 + ksb) << 13) + ib] = lo;
    B2p[((tb + 8 + ksb) << 13) + ib] = hi;
  }
  if (k0 == 0 && threadIdx.x < 64) {
    int n = n0 + threadIdx.x;
    if (n < NPAIRS) cdf[n] = fcb[2 * n] - fcb[2 * n + 1];
  }
}

// ------- A prep: x (f32 [4096][256]) -> A2p packed bf16 [mt][ks][128][64],
//   pre-swizzled; ks 0..3 = hi, 4..7 = hi, 8..11 = lo  (A' = [hi|hi|lo]) -------
__global__ __launch_bounds__(256) void k_asplit(const float* __restrict__ x,
                                                unsigned short* __restrict__ A2p) {
  int idx = blockIdx.x * 256 + threadIdx.x;      // 262144 threads total
  int m = idx >> 6;
  int k4 = (idx & 63) << 2;
  float4 v = *(const float4*)&x[(size_t)m * DIM + k4];
  float vv[4] = {v.x, v.y, v.z, v.w};
  unsigned short h_[4], l_[4];
  #pragma unroll
  for (int j = 0; j < 4; ++j) {
    h_[j] = f2bf(vv[j]);
    l_[j] = f2bf(vv[j] - bf2f(h_[j]));
  }
  ushort4 hi = make_ushort4(h_[0], h_[1], h_[2], h_[3]);
  ushort4 lo = make_ushort4(l_[0], l_[1], l_[2], l_[3]);
  int mt = m >> 7, mm = m & 127;
  int kk = k4 & 63;
  int s = kk >> 3, e = kk & 7;        // e in {0,4}
  int ss = s ^ (mm & 7);
  size_t ib = ((size_t)mm << 6) + (ss << 3) + e;
  int ksb = k4 >> 6;
  size_t tb = (size_t)mt * KSTEPS;
  *(ushort4*)&A2p[((tb + ksb)     << 13) + ib] = hi;
  *(ushort4*)&A2p[((tb + 4 + ksb) << 13) + ib] = hi;
  *(ushort4*)&A2p[((tb + 8 + ksb) << 13) + ib] = lo;
}

// ---------------- fp32 tiled GEMM: C(Mx256) = A(Mx256) * B(256x256) ----------------
__global__ __launch_bounds__(256) void k_gemm_h(const float* __restrict__ A,
                                                const float* __restrict__ Bm,
                                                float* __restrict__ C) {
  __shared__ float As[16][64];
  __shared__ float Bs[16][64];
  int tid = threadIdx.x;
  int rowBase = blockIdx.x * 64, colBase = blockIdx.y * 64;
  int tx = tid & 15, ty = tid >> 4;
  int ar = tid >> 2, ac = (tid & 3) << 2;
  int bkr = tid >> 6, bcc = tid & 63;
  float acc[4][4] = {{0.f}};
  for (int k0 = 0; k0 < DIM; k0 += 16) {
    float4 av = *(const float4*)&A[(size_t)(rowBase + ar) * DIM + k0 + ac];
    As[ac+0][ar] = av.x; As[ac+1][ar] = av.y; As[ac+2][ar] = av.z; As[ac+3][ar] = av.w;
    #pragma unroll
    for (int j = 0; j < 4; ++j)
      Bs[bkr + 4*j][bcc] = Bm[(size_t)(k0 + bkr + 4*j) * 256 + colBase + bcc];
    __syncthreads();
    #pragma unroll
    for (int kk = 0; kk < 16; ++kk) {
      float4 a4 = *(const float4*)&As[kk][ty << 2];
      float4 b4 = *(const float4*)&Bs[kk][tx << 2];
      float a[4] = {a4.x, a4.y, a4.z, a4.w};
      float b[4] = {b4.x, b4.y, b4.z, b4.w};
      #pragma unroll
      for (int i = 0; i < 4; ++i)
        #pragma unroll
        for (int j = 0; j < 4; ++j) acc[i][j] = fmaf(a[i], b[j], acc[i][j]);
    }
    __syncthreads();
  }
  #pragma unroll
  for (int i = 0; i < 4; ++i) {
    int r = rowBase + (ty << 2) + i;
    #pragma unroll
    for (int j = 0; j < 4; ++j)
      C[(size_t)r * 256 + colBase + (tx << 2) + j] = acc[i][j];
  }
}

// ------- pair GEMM via bf16x3-split MFMA -------
// 128x128 tile, BK=64, double-buffered LDS, 2-phase counted pipeline.
// A2p/B2p: packed pre-swizzled tiles -> every global_load_lds is 1KB contiguous.
__global__ __launch_bounds__(256, 2) void k_pairs_mfma(
    const unsigned short* __restrict__ A2p, const unsigned short* __restrict__ B2p,
    const float* __restrict__ xf,  const float* __restrict__ Wdn,
    const float* __restrict__ cdf, const float* __restrict__ gumbel,
    uint8_t* __restrict__ adjb) {
  __shared__ unsigned short As[2][8192];   // 2 x 16 KB
  __shared__ unsigned short Bs[2][8192];   // 2 x 16 KB
  int tid = threadIdx.x;
  int wv = tid >> 6, ln = tid & 63;
  // bijective XCD swizzle: 2048 blocks, 8 XCDs -> 256-block contiguous chunks
  int lin = blockIdx.x + (blockIdx.y << 5);
  int swz = (lin & 7) * 256 + (lin >> 3);
  int mt = swz & 31, nt = swz >> 5;
  int m0 = mt << 7, n0 = nt << 7;
  int wm = wv >> 1, wn = wv & 1;           // wave owns 64x64 sub-tile
  int frow = ln & 15, fg = ln >> 4;

  f32x4 zero = {0.f, 0.f, 0.f, 0.f};
  f32x4 acc[4][4];
  #pragma unroll
  for (int i = 0; i < 4; ++i)
    #pragma unroll
    for (int j = 0; j < 4; ++j) acc[i][j] = zero;

  const unsigned short* abase = A2p + (((size_t)mt * KSTEPS) << 13);
  const unsigned short* bbase = B2p + (((size_t)nt * KSTEPS) << 13);

  auto stage = [&](int buf, int ks) {
    const unsigned short* a_ = abase + ((size_t)ks << 13);
    const unsigned short* b_ = bbase + ((size_t)ks << 13);
    #pragma unroll
    for (int q = 0; q < 4; ++q) {
      int off = ((wv * 4 + q) << 9) + (ln << 3);   // ushort units; 16B/lane, linear
      __builtin_amdgcn_global_load_lds(AS1(a_ + off), AS3(&As[buf][off]), 16, 0, 0);
      __builtin_amdgcn_global_load_lds(AS1(b_ + off), AS3(&Bs[buf][off]), 16, 0, 0);
    }
  };

  stage(0, 0);
  __syncthreads();               // implicit vmcnt(0): buf0 ready
  int cur = 0;
  for (int ks = 0; ks < KSTEPS; ++ks) {
    if (ks < KSTEPS - 1) stage(cur ^ 1, ks + 1);   // issue next tile early
    #pragma unroll
    for (int kk2 = 0; kk2 < 2; ++kk2) {
      bf16x8 af[4], bfr[4];
      #pragma unroll
      for (int mi = 0; mi < 4; ++mi) {
        int r = (wm << 6) + (mi << 4) + frow;
        int ss = (kk2 * 4 + fg) ^ (r & 7);         // 2-way bank aliasing (free)
        af[mi] = *(const bf16x8*)&As[cur][(r << 6) + (ss << 3)];
      }
      #pragma unroll
      for (int ni = 0; ni < 4; ++ni) {
        int r = (wn << 6) + (ni << 4) + frow;
        int ss = (kk2 * 4 + fg) ^ (r & 7);
        bfr[ni] = *(const bf16x8*)&Bs[cur][(r << 6) + (ss << 3)];
      }
      #pragma unroll
      for (int mi = 0; mi < 4; ++mi)
        #pragma unroll
        for (int ni = 0; ni < 4; ++ni)
          acc[mi][ni] = __builtin_amdgcn_mfma_f32_16x16x32_bf16(
              af[mi], bfr[ni], acc[mi][ni], 0, 0, 0);
    }
    __syncthreads();             // drains next-tile loads + joins waves
    cur ^= 1;
  }

  // epilogue: D-frag layout col=lane&15, row=(lane>>4)*4+reg (m89-verified)
  int lr4 = fg << 2;
  int lc  = frow;
  int sel = ln & 3;
  #pragma unroll
  for (int ni = 0; ni < 4; ++ni) {
    int c = n0 + (wn << 6) + (ni << 4) + lc;
    bool cok = (c < NPAIRS);                 // uniform per 16-lane group
    float cd = cok ? cdf[c] : 0.f;
    #pragma unroll
    for (int mi = 0; mi < 4; ++mi) {
      #pragma unroll
      for (int jj = 0; jj < 4; ++jj) {
        int r = m0 + (wm << 6) + (mi << 4) + lr4 + jj;
        unsigned res = 0;
        if (cok) {
          float dlt = acc[mi][ni][jj] + cd;
          float2 g = *(const float2*)&gumbel[((size_t)r * NPAIRS + c) * 2];
          float l0 = EPS_G - __logf(g.x + EPS_G);
          float l1 = EPS_G - __logf(g.y + EPS_G);
          float thr = __logf(__fdividef(l0, l1));
          float diff = dlt - thr;
          if (__builtin_expect(fabsf(diff) < MARGIN, 0)) {
            // near-threshold: exact fp32 recompute (rare)
            const float4* xr4 = (const float4*)(xf + (size_t)r * DIM);
            const float4* wr4 = (const float4*)(Wdn + (size_t)c * DIM);
            float dot = 0.f;
            #pragma unroll 16
            for (int k = 0; k < DIM / 4; ++k) {
              float4 a = xr4[k], b = wr4[k];
              dot = fmaf(a.x, b.x, dot); dot = fmaf(a.y, b.y, dot);
              dot = fmaf(a.z, b.z, dot); dot = fmaf(a.w, b.w, dot);
            }
            float l0p = EPS_G - logf(g.x + EPS_G);
            float l1p = EPS_G - logf(g.y + EPS_G);
            res = (dot + cd >= logf(l0p / l1p)) ? 1u : 0u;
          } else {
            res = (diff >= 0.f) ? 1u : 0u;
          }
        }
        // merge 4 lanes -> one dword store (lanes 0,4,8,12 of each 16-group)
        unsigned w32 = res
                     | (__shfl_down(res, 1, 64) << 8)
                     | (__shfl_down(res, 2, 64) << 16)
                     | (__shfl_down(res, 3, 64) << 24);
        if (sel == 0 && cok)
          *(unsigned*)&adjb[(size_t)r * NPAIRS + c] = w32;
      }
    }
  }
}

// ---------------- per-row attention dots: one wave per node ----------------
__global__ __launch_bounds__(256) void k_rowdot(const float* __restrict__ h,
                                                const float* __restrict__ asrc,
                                                const float* __restrict__ adst,
                                                float* __restrict__ a_s,
                                                float* __restrict__ a_d) {
  int wid = threadIdx.x >> 6, lane = threadIdx.x & 63;
  int n = blockIdx.x * 4 + wid;
  float4 hv = *(const float4*)&h[(size_t)n * DIM + lane * 4];
  float4 s4 = *(const float4*)&asrc[lane * 4];
  float4 d4 = *(const float4*)&adst[lane * 4];
  float vs = hv.x*s4.x + hv.y*s4.y + hv.z*s4.z + hv.w*s4.w;
  float vd = hv.x*d4.x + hv.y*d4.y + hv.z*d4.z + hv.w*d4.w;
  #pragma unroll
  for (int o = 1; o < 64; o <<= 1) {
    vs += __shfl_xor(vs, o, 64);
    vd += __shfl_xor(vd, o, 64);
  }
  if (lane == 0) { a_s[n] = vs; a_d[n] = vd; }
}

// ------- segment softmax + aggregation: one WAVE per dst node -------
__global__ __launch_bounds__(256) void k_agg(const float* __restrict__ h,
                                             const float* __restrict__ a_s,
                                             const float* __restrict__ a_d,
                                             const int* __restrict__ offs,
                                             const int* __restrict__ srcs,
                                             const float* __restrict__ bias,
                                             float* __restrict__ xout) {
  int wid  = threadIdx.x >> 6;
  int lane = threadIdx.x & 63;
  int n = blockIdx.x * 4 + wid;
  int beg = offs[n], end = offs[n + 1];
  float ad = a_d[n];

  float m = -3.0e38f;
  for (int i = beg + lane; i < end; i += 64) {
    float e = a_s[srcs[i]] + ad;
    e = (e >= 0.f) ? e : NEG_SLOPE * e;
    m = fmaxf(m, e);
  }
  #pragma unroll
  for (int o = 1; o < 64; o <<= 1) m = fmaxf(m, __shfl_xor(m, o, 64));

  float s = 0.f;
  for (int i = beg + lane; i < end; i += 64) {
    float e = a_s[srcs[i]] + ad;
    e = (e >= 0.f) ? e : NEG_SLOPE * e;
    s += expf(e - m);
  }
  #pragma unroll
  for (int o = 1; o < 64; o <<= 1) s += __shfl_xor(s, o, 64);

  float4 acc = make_float4(0.f, 0.f, 0.f, 0.f);
  for (int base = beg; base < end; base += 64) {
    int cnt = min(64, end - base);
    int mysrc = 0;
    float w = 0.f;
    if (base + lane < end) {
      mysrc = srcs[base + lane];
      float e = a_s[mysrc] + ad;
      e = (e >= 0.f) ? e : NEG_SLOPE * e;
      w = expf(e - m) / s;
    }
    int j = 0;
    for (; j + 4 <= cnt; j += 4) {
      float al0 = __shfl(w, j,     64), al1 = __shfl(w, j + 1, 64);
      float al2 = __shfl(w, j + 2, 64), al3 = __shfl(w, j + 3, 64);
      int   s0  = __shfl(mysrc, j,     64), s1 = __shfl(mysrc, j + 1, 64);
      int   s2  = __shfl(mysrc, j + 2, 64), s3 = __shfl(mysrc, j + 3, 64);
      float4 h0 = *(const float4*)&h[(size_t)s0 * DIM + lane * 4];
      float4 h1 = *(const float4*)&h[(size_t)s1 * DIM + lane * 4];
      float4 h2 = *(const float4*)&h[(size_t)s2 * DIM + lane * 4];
      float4 h3 = *(const float4*)&h[(size_t)s3 * DIM + lane * 4];
      acc.x = fmaf(al0, h0.x, fmaf(al1, h1.x, fmaf(al2, h2.x, fmaf(al3, h3.x, acc.x))));
      acc.y = fmaf(al0, h0.y, fmaf(al1, h1.y, fmaf(al2, h2.y, fmaf(al3, h3.y, acc.y))));
      acc.z = fmaf(al0, h0.z, fmaf(al1, h1.z, fmaf(al2, h2.z, fmaf(al3, h3.z, acc.z))));
      acc.w = fmaf(al0, h0.w, fmaf(al1, h1.w, fmaf(al2, h2.w, fmaf(al3, h3.w, acc.w))));
    }
    for (; j < cnt; ++j) {
      float alpha = __shfl(w, j, 64);
      int   sj    = __shfl(mysrc, j, 64);
      float4 hv = *(const float4*)&h[(size_t)sj * DIM + lane * 4];
      acc.x = fmaf(alpha, hv.x, acc.x);
      acc.y = fmaf(alpha, hv.y, acc.y);
      acc.z = fmaf(alpha, hv.z, acc.z);
      acc.w = fmaf(alpha, hv.w, acc.w);
    }
  }
  float4 bv = *(const float4*)&bias[lane * 4];
  acc.x += bv.x; acc.y += bv.y; acc.z += bv.z; acc.w += bv.w;
  *(float4*)&xout[(size_t)n * DIM + lane * 4] = acc;
}

// ---------------- expand adj bytes → symmetric 128x128 output ----------------
__global__ __launch_bounds__(256) void k_expand(const uint8_t* __restrict__ adjb,
                                                float* __restrict__ out) {
  int n = blockIdx.x;
  const uint8_t* ab = adjb + (size_t)n * NPAIRS;
  float4* o = (float4*)(out + (size_t)n * 16384);
  for (int q = threadIdx.x; q < 4096; q += 256) {
    int i = q >> 5;            // row
    int j0 = (q & 31) * 4;
    float v[4];
    #pragma unroll
    for (int j = 0; j < 4; ++j) {
      int jj = j0 + j;
      float x = 0.f;
      if (i < jj)      x = (float)ab[i * (255 - i) / 2 + (jj - i - 1)];
      else if (i > jj) x = (float)ab[jj * (255 - jj) / 2 + (i - jj - 1)];
      v[j] = x;
    }
    o[q] = make_float4(v[0], v[1], v[2], v[3]);
  }
}

extern "C" void kernel_launch(void* const* d_in, const int* in_sizes, int n_in,
                              void* d_out, int out_size, void* d_ws, size_t ws_size,
                              hipStream_t stream) {
  const float* x      = (const float*)d_in[0];
  const int*   ei     = (const int*)d_in[1];
  const float* gumbel = (const float*)d_in[2];
  const float* gatW   = (const float*)d_in[3];
  const float* a_src  = (const float*)d_in[4];
  const float* a_dst  = (const float*)d_in[5];
  const float* gatB   = (const float*)d_in[6];
  const float* fcW    = (const float*)d_in[7];
  const float* fcb    = (const float*)d_in[8];
  float* out = (float*)d_out;

  char* ws = (char*)d_ws;
  size_t off = 0;
  auto alloc = [&](size_t bytes) -> void* {
    void* p = ws + off;
    off += (bytes + 255) & ~(size_t)255;
    return p;
  };
  float* xb0   = (float*)alloc((size_t)NNODES * DIM * 4);
  float* xb1   = (float*)alloc((size_t)NNODES * DIM * 4);
  float* h     = (float*)alloc((size_t)NNODES * DIM * 4);
  float* as_   = (float*)alloc(NNODES * 4);
  float* ad_   = (float*)alloc(NNODES * 4);
  int*   deg   = (int*)alloc(NNODES * 4);
  int*   offs  = (int*)alloc((NNODES + 1) * 4);
  int*   cursor= (int*)alloc(NNODES * 4);
  int*   srcs  = (int*)alloc((size_t)M_EDGES * 4);
  float* Wdn   = (float*)alloc((size_t)NPAD * DIM * 4);            // n-major fp32 fallback
  unsigned short* B2p = (unsigned short*)alloc((size_t)(NPAD/128) * KSTEPS * 8192 * 2);
  unsigned short* A2p = (unsigned short*)alloc((size_t)(NNODES/128) * KSTEPS * 8192 * 2);
  float* cdf   = (float*)alloc(NPAIRS * 4);
  uint8_t* adjb= (uint8_t*)alloc((size_t)NNODES * NPAIRS);

  dim3 b256(256);

  hipMemsetAsync(deg, 0, NNODES * 4, stream);
  k_wprep<<<dim3(NPAD / 64, DIM / 64), b256, 0, stream>>>(fcW, fcb, Wdn, B2p, cdf);
  k_deg<<<dim3((M_EDGES + 255) / 256), b256, 0, stream>>>(ei, deg);
  k_scan<<<dim3(1), dim3(1024), 0, stream>>>(deg, offs, cursor);
  k_scatter<<<dim3((M_EDGES + 255) / 256), b256, 0, stream>>>(ei, cursor, srcs);

  const float* xin = x;
  float* bufs[2] = {xb0, xb1};
  for (int l = 0; l < 3; ++l) {
    float* xout = bufs[l & 1];
    k_gemm_h<<<dim3(64, 4), b256, 0, stream>>>(xin, gatW + (size_t)l * DIM * DIM, h);
    k_rowdot<<<dim3(NNODES / 4), b256, 0, stream>>>(h, a_src + (size_t)l * DIM,
                                                    a_dst + (size_t)l * DIM, as_, ad_);
    k_agg<<<dim3(NNODES / 4), b256, 0, stream>>>(h, as_, ad_, offs, srcs,
                                                 gatB + (size_t)l * DIM, xout);
    xin = xout;
  }

  k_asplit<<<dim3(NNODES * DIM / 4 / 256), b256, 0, stream>>>(xin, A2p);
  k_pairs_mfma<<<dim3(32, 64), b256, 0, stream>>>(A2p, B2p, xin, Wdn, cdf, gumbel, adjb);
  k_expand<<<dim3(NNODES), b256, 0, stream>>>(adjb, out);
}

// Round 3
// 876.702 us; speedup vs baseline: 1.0933x; 1.0933x over previous
//
#include <hip/hip_runtime.h>
#include <cstdint>
#include <cstddef>

#define NNODES   4096        // B
#define DIM      256         // D
#define NPAIRS   8128        // 128*127/2
#define NPAD     8192        // padded pair columns
#define CHW      4096        // chunk width (pair cols per chunk)
#define NEDGE_IN 131072      // E
#define M_EDGES  (NEDGE_IN + NNODES)
#define NEG_SLOPE 0.2f
#define EPS_G     1e-10f
#define KSTEPS   12          // 768 / 64
#define MARGIN   1e-3f       // |dlt-thr| below this -> exact fp32 recompute

#define AS3(p) ((__attribute__((address_space(3))) void*)(p))
#define AS1(p) ((const __attribute__((address_space(1))) void*)(p))

typedef __attribute__((ext_vector_type(8))) short bf16x8;   // 8 bf16 = 4 VGPR
typedef __attribute__((ext_vector_type(4))) float f32x4;

// round-to-nearest-even fp32 -> bf16 (bit math, deterministic)
__device__ __forceinline__ unsigned short f2bf(float f) {
  unsigned u = __float_as_uint(f);
  unsigned r = u + 0x7fffu + ((u >> 16) & 1u);
  return (unsigned short)(r >> 16);
}
__device__ __forceinline__ float bf2f(unsigned short h) {
  return __uint_as_float(((unsigned)h) << 16);
}

// ---------------- CSR build ----------------
__global__ void k_deg(const int* __restrict__ ei, int* __restrict__ deg) {
  int e = blockIdx.x * 256 + threadIdx.x;
  if (e >= M_EDGES) return;
  int dst = (e < NEDGE_IN) ? ei[NEDGE_IN + e] : (e - NEDGE_IN);
  atomicAdd(&deg[dst], 1);
}

__global__ void k_scan(const int* __restrict__ deg, int* __restrict__ offs,
                       int* __restrict__ cursor) {
  __shared__ int lds[1024];
  int t = threadIdx.x;
  int4 d = *(const int4*)&deg[t * 4];
  int s = d.x + d.y + d.z + d.w;
  lds[t] = s;
  __syncthreads();
  for (int off = 1; off < 1024; off <<= 1) {
    int v = 0;
    if (t >= off) v = lds[t - off];
    __syncthreads();
    if (t >= off) lds[t] += v;
    __syncthreads();
  }
  int base = lds[t] - s;               // exclusive prefix
  int o0 = base, o1 = o0 + d.x, o2 = o1 + d.y, o3 = o2 + d.z;
  offs[t*4+0] = o0; offs[t*4+1] = o1; offs[t*4+2] = o2; offs[t*4+3] = o3;
  cursor[t*4+0] = o0; cursor[t*4+1] = o1; cursor[t*4+2] = o2; cursor[t*4+3] = o3;
  if (t == 1023) offs[4096] = lds[1023];
}

__global__ void k_scatter(const int* __restrict__ ei, int* __restrict__ cursor,
                          int* __restrict__ srcs) {
  int e = blockIdx.x * 256 + threadIdx.x;
  if (e >= M_EDGES) return;
  int src, dst;
  if (e < NEDGE_IN) { src = ei[e]; dst = ei[NEDGE_IN + e]; }
  else              { src = dst = e - NEDGE_IN; }
  int pos = atomicAdd(&cursor[dst], 1);
  srcs[pos] = src;
}

// ------- W prep: fcW (k-major) -> Wdn (f32 n-major [NPAD][256]),
//   B2p packed bf16 tiles [nt][ks][128][64] pre-swizzled (slot ^= row&7), cdf.
//   K-step order: ks 0..3 = hi, 4..7 = lo, 8..11 = hi  (B' = [hi|lo|hi]) -------
__global__ __launch_bounds__(256) void k_wprep(const float* __restrict__ fcW,
                                               const float* __restrict__ fcb,
                                               float* __restrict__ Wdn,
                                               unsigned short* __restrict__ B2p,
                                               float* __restrict__ cdf) {
  __shared__ float t[64][65];
  int n0 = blockIdx.x * 64;    // 0..8128 step 64
  int k0 = blockIdx.y * 64;    // 0..192  step 64
  for (int i = threadIdx.x; i < 4096; i += 256) {
    int r = i >> 6, c = i & 63;
    int n = n0 + c;
    float d = 0.f;
    if (n < NPAIRS) {
      const float* p = fcW + (size_t)(k0 + r) * (2 * NPAIRS) + 2 * n;
      d = p[0] - p[1];
    }
    t[r][c] = d;
  }
  __syncthreads();
  int ksb = k0 >> 6;           // 0..3
  for (int i = threadIdx.x; i < 4096; i += 256) {
    int rn = i >> 6, ck = i & 63;
    int n = n0 + rn, k = k0 + ck;
    float d = t[ck][rn];
    Wdn[(size_t)n * DIM + k] = d;
    unsigned short hi = f2bf(d);
    unsigned short lo = f2bf(d - bf2f(hi));
    int nt = n >> 7, nn = n & 127;
    int s = ck >> 3, e = ck & 7;
    int ss = s ^ (nn & 7);
    size_t ib = ((size_t)nn << 6) + (ss << 3) + e;
    size_t tb = (size_t)nt * KSTEPS;
    B2p[((tb + ksb)     << 13) + ib] = hi;
    B2p[((tb + 4 + ksb) << 13) + ib] = lo;
    B2p[((tb + 8 + ksb) << 13) + ib] = hi;
  }
  if (k0 == 0 && threadIdx.x < 64) {
    int n = n0 + threadIdx.x;
    if (n < NPAIRS) cdf[n] = fcb[2 * n] - fcb[2 * n + 1];
  }
}

// ------- A prep: x (f32 [4096][256]) -> A2p packed bf16 [mt][ks][128][64],
//   pre-swizzled; ks 0..3 = hi, 4..7 = hi, 8..11 = lo  (A' = [hi|hi|lo]) -------
__global__ __launch_bounds__(256) void k_asplit(const float* __restrict__ x,
                                                unsigned short* __restrict__ A2p) {
  int idx = blockIdx.x * 256 + threadIdx.x;      // 262144 threads total
  int m = idx >> 6;
  int k4 = (idx & 63) << 2;
  float4 v = *(const float4*)&x[(size_t)m * DIM + k4];
  float vv[4] = {v.x, v.y, v.z, v.w};
  unsigned short h_[4], l_[4];
  #pragma unroll
  for (int j = 0; j < 4; ++j) {
    h_[j] = f2bf(vv[j]);
    l_[j] = f2bf(vv[j] - bf2f(h_[j]));
  }
  ushort4 hi = make_ushort4(h_[0], h_[1], h_[2], h_[3]);
  ushort4 lo = make_ushort4(l_[0], l_[1], l_[2], l_[3]);
  int mt = m >> 7, mm = m & 127;
  int kk = k4 & 63;
  int s = kk >> 3, e = kk & 7;        // e in {0,4}
  int ss = s ^ (mm & 7);
  size_t ib = ((size_t)mm << 6) + (ss << 3) + e;
  int ksb = k4 >> 6;
  size_t tb = (size_t)mt * KSTEPS;
  *(ushort4*)&A2p[((tb + ksb)     << 13) + ib] = hi;
  *(ushort4*)&A2p[((tb + 4 + ksb) << 13) + ib] = hi;
  *(ushort4*)&A2p[((tb + 8 + ksb) << 13) + ib] = lo;
}

// ---------------- fp32 tiled GEMM: C(Mx256) = A(Mx256) * B(256x256) ----------------
__global__ __launch_bounds__(256) void k_gemm_h(const float* __restrict__ A,
                                                const float* __restrict__ Bm,
                                                float* __restrict__ C) {
  __shared__ float As[16][64];
  __shared__ float Bs[16][64];
  int tid = threadIdx.x;
  int rowBase = blockIdx.x * 64, colBase = blockIdx.y * 64;
  int tx = tid & 15, ty = tid >> 4;
  int ar = tid >> 2, ac = (tid & 3) << 2;
  int bkr = tid >> 6, bcc = tid & 63;
  float acc[4][4] = {{0.f}};
  for (int k0 = 0; k0 < DIM; k0 += 16) {
    float4 av = *(const float4*)&A[(size_t)(rowBase + ar) * DIM + k0 + ac];
    As[ac+0][ar] = av.x; As[ac+1][ar] = av.y; As[ac+2][ar] = av.z; As[ac+3][ar] = av.w;
    #pragma unroll
    for (int j = 0; j < 4; ++j)
      Bs[bkr + 4*j][bcc] = Bm[(size_t)(k0 + bkr + 4*j) * 256 + colBase + bcc];
    __syncthreads();
    #pragma unroll
    for (int kk = 0; kk < 16; ++kk) {
      float4 a4 = *(const float4*)&As[kk][ty << 2];
      float4 b4 = *(const float4*)&Bs[kk][tx << 2];
      float a[4] = {a4.x, a4.y, a4.z, a4.w};
      float b[4] = {b4.x, b4.y, b4.z, b4.w};
      #pragma unroll
      for (int i = 0; i < 4; ++i)
        #pragma unroll
        for (int j = 0; j < 4; ++j) acc[i][j] = fmaf(a[i], b[j], acc[i][j]);
    }
    __syncthreads();
  }
  #pragma unroll
  for (int i = 0; i < 4; ++i) {
    int r = rowBase + (ty << 2) + i;
    #pragma unroll
    for (int j = 0; j < 4; ++j)
      C[(size_t)r * 256 + colBase + (tx << 2) + j] = acc[i][j];
  }
}

// ------- pair GEMM via bf16x3-split MFMA -------
// 128x128 tile, BK=64, double-buffered LDS, 2-phase pipeline.
// Epilogue: store dlt+cdf as f32 into Dlt chunk [4096][CHW]. No loads, no logs.
__global__ __launch_bounds__(256, 2) void k_pairs_mfma(
    const unsigned short* __restrict__ A2p, const unsigned short* __restrict__ B2p,
    const float* __restrict__ cdf, float* __restrict__ Dlt, int chunk) {
  __shared__ unsigned short As[2][8192];   // 2 x 16 KB
  __shared__ unsigned short Bs[2][8192];   // 2 x 16 KB
  int tid = threadIdx.x;
  int wv = tid >> 6, ln = tid & 63;
  int mt = blockIdx.x;               // 0..31
  int ntl = blockIdx.y;              // 0..31 (local)
  int nt = chunk * 32 + ntl;         // global B tile
  int m0 = mt << 7;
  int wm = wv >> 1, wn = wv & 1;     // wave owns 64x64 sub-tile
  int frow = ln & 15, fg = ln >> 4;

  f32x4 zero = {0.f, 0.f, 0.f, 0.f};
  f32x4 acc[4][4];
  #pragma unroll
  for (int i = 0; i < 4; ++i)
    #pragma unroll
    for (int j = 0; j < 4; ++j) acc[i][j] = zero;

  const unsigned short* abase = A2p + (((size_t)mt * KSTEPS) << 13);
  const unsigned short* bbase = B2p + (((size_t)nt * KSTEPS) << 13);

  auto stage = [&](int buf, int ks) {
    const unsigned short* a_ = abase + ((size_t)ks << 13);
    const unsigned short* b_ = bbase + ((size_t)ks << 13);
    #pragma unroll
    for (int q = 0; q < 4; ++q) {
      int off = ((wv * 4 + q) << 9) + (ln << 3);   // ushort units; 16B/lane, linear
      __builtin_amdgcn_global_load_lds(AS1(a_ + off), AS3(&As[buf][off]), 16, 0, 0);
      __builtin_amdgcn_global_load_lds(AS1(b_ + off), AS3(&Bs[buf][off]), 16, 0, 0);
    }
  };

  stage(0, 0);
  __syncthreads();               // implicit vmcnt(0): buf0 ready
  int cur = 0;
  for (int ks = 0; ks < KSTEPS; ++ks) {
    if (ks < KSTEPS - 1) stage(cur ^ 1, ks + 1);   // issue next tile early
    #pragma unroll
    for (int kk2 = 0; kk2 < 2; ++kk2) {
      bf16x8 af[4], bfr[4];
      #pragma unroll
      for (int mi = 0; mi < 4; ++mi) {
        int r = (wm << 6) + (mi << 4) + frow;
        int ss = (kk2 * 4 + fg) ^ (r & 7);         // 2-way bank aliasing (free)
        af[mi] = *(const bf16x8*)&As[cur][(r << 6) + (ss << 3)];
      }
      #pragma unroll
      for (int ni = 0; ni < 4; ++ni) {
        int r = (wn << 6) + (ni << 4) + frow;
        int ss = (kk2 * 4 + fg) ^ (r & 7);
        bfr[ni] = *(const bf16x8*)&Bs[cur][(r << 6) + (ss << 3)];
      }
      #pragma unroll
      for (int mi = 0; mi < 4; ++mi)
        #pragma unroll
        for (int ni = 0; ni < 4; ++ni)
          acc[mi][ni] = __builtin_amdgcn_mfma_f32_16x16x32_bf16(
              af[mi], bfr[ni], acc[mi][ni], 0, 0, 0);
    }
    __syncthreads();             // drains next-tile loads + joins waves
    cur ^= 1;
  }

  // epilogue: D-frag layout col=lane&15, row=(lane>>4)*4+reg (m89-verified).
  // Pure f32 stores of dlt = acc + cdf. 64 dword stores/thread, fire-and-forget.
  int lr4 = fg << 2;
  #pragma unroll
  for (int ni = 0; ni < 4; ++ni) {
    int cg = (nt << 7) + (wn << 6) + (ni << 4) + frow;    // global pair col
    int cl = (ntl << 7) + (wn << 6) + (ni << 4) + frow;   // local col in chunk
    float cd = (cg < NPAIRS) ? cdf[cg] : 0.f;
    #pragma unroll
    for (int mi = 0; mi < 4; ++mi) {
      #pragma unroll
      for (int jj = 0; jj < 4; ++jj) {
        int r = m0 + (wm << 6) + (mi << 4) + lr4 + jj;
        Dlt[((size_t)r << 12) + cl] = acc[mi][ni][jj] + cd;
      }
    }
  }
}

// ------- streaming decision kernel: dlt vs gumbel threshold -> adjb bytes -------
// Pure streaming: coalesced float4 loads, 4 independent quads/thread for MLP,
// no LDS, low VGPR -> high occupancy. Rare near-threshold fp32 fallback.
__global__ __launch_bounds__(256) void k_decide(const float* __restrict__ Dlt,
                                                const float* __restrict__ gumbel,
                                                const float* __restrict__ xf,
                                                const float* __restrict__ Wdn,
                                                const float* __restrict__ cdf,
                                                uint8_t* __restrict__ adjb,
                                                int c0) {
  int base = blockIdx.x * 1024 + threadIdx.x;
  #pragma unroll 1
  for (int s = 0; s < 2; ++s) {
    int q0 = (s << 21) + base;            // 2 sweeps x 2048 blocks x 1024 quads
    #pragma unroll
    for (int j = 0; j < 4; ++j) {
      int q = q0 + (j << 8);
      int r  = q >> 10;                   // node row
      int cl = (q & 1023) << 2;           // local col (quad base)
      int c  = c0 + cl;                   // global pair col
      if (c >= NPAIRS) continue;          // NPAIRS % 4 == 0: quads all-or-nothing
      float4 d4 = *(const float4*)&Dlt[((size_t)r << 12) + cl];
      const float* gp = gumbel + ((size_t)r * NPAIRS + c) * 2;
      float4 g01 = *(const float4*)gp;
      float4 g23 = *(const float4*)(gp + 4);
      float dl[4] = {d4.x, d4.y, d4.z, d4.w};
      float u0[4] = {g01.x, g01.z, g23.x, g23.z};
      float u1[4] = {g01.y, g01.w, g23.y, g23.w};
      unsigned res = 0;
      #pragma unroll
      for (int t = 0; t < 4; ++t) {
        float l0 = EPS_G - __logf(u0[t] + EPS_G);
        float l1 = EPS_G - __logf(u1[t] + EPS_G);
        float thr = __logf(__fdividef(l0, l1));
        float diff = dl[t] - thr;
        unsigned bit;
        if (__builtin_expect(fabsf(diff) < MARGIN, 0)) {
          // near-threshold: exact fp32 recompute (rare)
          const float4* xr4 = (const float4*)(xf + (size_t)r * DIM);
          const float4* wr4 = (const float4*)(Wdn + (size_t)(c + t) * DIM);
          float dot = 0.f;
          #pragma unroll 16
          for (int k = 0; k < DIM / 4; ++k) {
            float4 a = xr4[k], b = wr4[k];
            dot = fmaf(a.x, b.x, dot); dot = fmaf(a.y, b.y, dot);
            dot = fmaf(a.z, b.z, dot); dot = fmaf(a.w, b.w, dot);
          }
          float l0p = EPS_G - logf(u0[t] + EPS_G);
          float l1p = EPS_G - logf(u1[t] + EPS_G);
          bit = (dot + cdf[c + t] >= logf(l0p / l1p)) ? 1u : 0u;
        } else {
          bit = (diff >= 0.f) ? 1u : 0u;
        }
        res |= bit << (8 * t);
      }
      *(unsigned*)&adjb[(size_t)r * NPAIRS + c] = res;
    }
  }
}

// ---------------- per-row attention dots: one wave per node ----------------
__global__ __launch_bounds__(256) void k_rowdot(const float* __restrict__ h,
                                                const float* __restrict__ asrc,
                                                const float* __restrict__ adst,
                                                float* __restrict__ a_s,
                                                float* __restrict__ a_d) {
  int wid = threadIdx.x >> 6, lane = threadIdx.x & 63;
  int n = blockIdx.x * 4 + wid;
  float4 hv = *(const float4*)&h[(size_t)n * DIM + lane * 4];
  float4 s4 = *(const float4*)&asrc[lane * 4];
  float4 d4 = *(const float4*)&adst[lane * 4];
  float vs = hv.x*s4.x + hv.y*s4.y + hv.z*s4.z + hv.w*s4.w;
  float vd = hv.x*d4.x + hv.y*d4.y + hv.z*d4.z + hv.w*d4.w;
  #pragma unroll
  for (int o = 1; o < 64; o <<= 1) {
    vs += __shfl_xor(vs, o, 64);
    vd += __shfl_xor(vd, o, 64);
  }
  if (lane == 0) { a_s[n] = vs; a_d[n] = vd; }
}

// ------- segment softmax + aggregation: one WAVE per dst node -------
__global__ __launch_bounds__(256) void k_agg(const float* __restrict__ h,
                                             const float* __restrict__ a_s,
                                             const float* __restrict__ a_d,
                                             const int* __restrict__ offs,
                                             const int* __restrict__ srcs,
                                             const float* __restrict__ bias,
                                             float* __restrict__ xout) {
  int wid  = threadIdx.x >> 6;
  int lane = threadIdx.x & 63;
  int n = blockIdx.x * 4 + wid;
  int beg = offs[n], end = offs[n + 1];
  float ad = a_d[n];

  float m = -3.0e38f;
  for (int i = beg + lane; i < end; i += 64) {
    float e = a_s[srcs[i]] + ad;
    e = (e >= 0.f) ? e : NEG_SLOPE * e;
    m = fmaxf(m, e);
  }
  #pragma unroll
  for (int o = 1; o < 64; o <<= 1) m = fmaxf(m, __shfl_xor(m, o, 64));

  float s = 0.f;
  for (int i = beg + lane; i < end; i += 64) {
    float e = a_s[srcs[i]] + ad;
    e = (e >= 0.f) ? e : NEG_SLOPE * e;
    s += expf(e - m);
  }
  #pragma unroll
  for (int o = 1; o < 64; o <<= 1) s += __shfl_xor(s, o, 64);

  float4 acc = make_float4(0.f, 0.f, 0.f, 0.f);
  for (int base = beg; base < end; base += 64) {
    int cnt = min(64, end - base);
    int mysrc = 0;
    float w = 0.f;
    if (base + lane < end) {
      mysrc = srcs[base + lane];
      float e = a_s[mysrc] + ad;
      e = (e >= 0.f) ? e : NEG_SLOPE * e;
      w = expf(e - m) / s;
    }
    int j = 0;
    for (; j + 4 <= cnt; j += 4) {
      float al0 = __shfl(w, j,     64), al1 = __shfl(w, j + 1, 64);
      float al2 = __shfl(w, j + 2, 64), al3 = __shfl(w, j + 3, 64);
      int   s0  = __shfl(mysrc, j,     64), s1 = __shfl(mysrc, j + 1, 64);
      int   s2  = __shfl(mysrc, j + 2, 64), s3 = __shfl(mysrc, j + 3, 64);
      float4 h0 = *(const float4*)&h[(size_t)s0 * DIM + lane * 4];
      float4 h1 = *(const float4*)&h[(size_t)s1 * DIM + lane * 4];
      float4 h2 = *(const float4*)&h[(size_t)s2 * DIM + lane * 4];
      float4 h3 = *(const float4*)&h[(size_t)s3 * DIM + lane * 4];
      acc.x = fmaf(al0, h0.x, fmaf(al1, h1.x, fmaf(al2, h2.x, fmaf(al3, h3.x, acc.x))));
      acc.y = fmaf(al0, h0.y, fmaf(al1, h1.y, fmaf(al2, h2.y, fmaf(al3, h3.y, acc.y))));
      acc.z = fmaf(al0, h0.z, fmaf(al1, h1.z, fmaf(al2, h2.z, fmaf(al3, h3.z, acc.z))));
      acc.w = fmaf(al0, h0.w, fmaf(al1, h1.w, fmaf(al2, h2.w, fmaf(al3, h3.w, acc.w))));
    }
    for (; j < cnt; ++j) {
      float alpha = __shfl(w, j, 64);
      int   sj    = __shfl(mysrc, j, 64);
      float4 hv = *(const float4*)&h[(size_t)sj * DIM + lane * 4];
      acc.x = fmaf(alpha, hv.x, acc.x);
      acc.y = fmaf(alpha, hv.y, acc.y);
      acc.z = fmaf(alpha, hv.z, acc.z);
      acc.w = fmaf(alpha, hv.w, acc.w);
    }
  }
  float4 bv = *(const float4*)&bias[lane * 4];
  acc.x += bv.x; acc.y += bv.y; acc.z += bv.z; acc.w += bv.w;
  *(float4*)&xout[(size_t)n * DIM + lane * 4] = acc;
}

// ---------------- expand adj bytes → symmetric 128x128 output ----------------
__global__ __launch_bounds__(256) void k_expand(const uint8_t* __restrict__ adjb,
                                                float* __restrict__ out) {
  int n = blockIdx.x;
  const uint8_t* ab = adjb + (size_t)n * NPAIRS;
  float4* o = (float4*)(out + (size_t)n * 16384);
  for (int q = threadIdx.x; q < 4096; q += 256) {
    int i = q >> 5;            // row
    int j0 = (q & 31) * 4;
    float v[4];
    #pragma unroll
    for (int j = 0; j < 4; ++j) {
      int jj = j0 + j;
      float x = 0.f;
      if (i < jj)      x = (float)ab[i * (255 - i) / 2 + (jj - i - 1)];
      else if (i > jj) x = (float)ab[jj * (255 - jj) / 2 + (i - jj - 1)];
      v[j] = x;
    }
    o[q] = make_float4(v[0], v[1], v[2], v[3]);
  }
}

extern "C" void kernel_launch(void* const* d_in, const int* in_sizes, int n_in,
                              void* d_out, int out_size, void* d_ws, size_t ws_size,
                              hipStream_t stream) {
  const float* x      = (const float*)d_in[0];
  const int*   ei     = (const int*)d_in[1];
  const float* gumbel = (const float*)d_in[2];
  const float* gatW   = (const float*)d_in[3];
  const float* a_src  = (const float*)d_in[4];
  const float* a_dst  = (const float*)d_in[5];
  const float* gatB   = (const float*)d_in[6];
  const float* fcW    = (const float*)d_in[7];
  const float* fcb    = (const float*)d_in[8];
  float* out = (float*)d_out;

  char* ws = (char*)d_ws;
  size_t off = 0;
  auto alloc = [&](size_t bytes) -> void* {
    void* p = ws + off;
    off += (bytes + 255) & ~(size_t)255;
    return p;
  };
  // total ≈ 140 MB
  float* xb0   = (float*)alloc((size_t)NNODES * DIM * 4);
  float* xb1   = (float*)alloc((size_t)NNODES * DIM * 4);
  float* h     = (float*)alloc((size_t)NNODES * DIM * 4);
  float* as_   = (float*)alloc(NNODES * 4);
  float* ad_   = (float*)alloc(NNODES * 4);
  int*   deg   = (int*)alloc(NNODES * 4);
  int*   offs  = (int*)alloc((NNODES + 1) * 4);
  int*   cursor= (int*)alloc(NNODES * 4);
  int*   srcs  = (int*)alloc((size_t)M_EDGES * 4);
  float* Wdn   = (float*)alloc((size_t)NPAD * DIM * 4);            // n-major fp32 fallback
  unsigned short* B2p = (unsigned short*)alloc((size_t)(NPAD/128) * KSTEPS * 8192 * 2);
  unsigned short* A2p = (unsigned short*)alloc((size_t)(NNODES/128) * KSTEPS * 8192 * 2);
  float* cdf   = (float*)alloc(NPAIRS * 4);
  float* Dlt   = (float*)alloc((size_t)NNODES * CHW * 4);          // 67 MB chunk buffer
  uint8_t* adjb= (uint8_t*)alloc((size_t)NNODES * NPAIRS);

  dim3 b256(256);

  hipMemsetAsync(deg, 0, NNODES * 4, stream);
  k_wprep<<<dim3(NPAD / 64, DIM / 64), b256, 0, stream>>>(fcW, fcb, Wdn, B2p, cdf);
  k_deg<<<dim3((M_EDGES + 255) / 256), b256, 0, stream>>>(ei, deg);
  k_scan<<<dim3(1), dim3(1024), 0, stream>>>(deg, offs, cursor);
  k_scatter<<<dim3((M_EDGES + 255) / 256), b256, 0, stream>>>(ei, cursor, srcs);

  const float* xin = x;
  float* bufs[2] = {xb0, xb1};
  for (int l = 0; l < 3; ++l) {
    float* xout = bufs[l & 1];
    k_gemm_h<<<dim3(64, 4), b256, 0, stream>>>(xin, gatW + (size_t)l * DIM * DIM, h);
    k_rowdot<<<dim3(NNODES / 4), b256, 0, stream>>>(h, a_src + (size_t)l * DIM,
                                                    a_dst + (size_t)l * DIM, as_, ad_);
    k_agg<<<dim3(NNODES / 4), b256, 0, stream>>>(h, as_, ad_, offs, srcs,
                                                 gatB + (size_t)l * DIM, xout);
    xin = xout;
  }

  k_asplit<<<dim3(NNODES * DIM / 4 / 256), b256, 0, stream>>>(xin, A2p);
  for (int ch = 0; ch < 2; ++ch) {
    k_pairs_mfma<<<dim3(32, 32), b256, 0, stream>>>(A2p, B2p, cdf, Dlt, ch);
    k_decide<<<dim3(2048), b256, 0, stream>>>(Dlt, gumbel, xin, Wdn, cdf, adjb,
                                              ch * CHW);
  }
  k_expand<<<dim3(NNODES), b256, 0, stream>>>(adjb, out);
}

// Round 4
// 747.613 us; speedup vs baseline: 1.2821x; 1.1727x over previous
//
#include <hip/hip_runtime.h>
#include <cstdint>
#include <cstddef>

#define NNODES   4096        // B
#define DIM      256         // D
#define NPAIRS   8128        // 128*127/2
#define NPAD     8192        // padded pair columns
#define NEDGE_IN 131072      // E
#define M_EDGES  (NEDGE_IN + NNODES)
#define NEG_SLOPE 0.2f
#define EPS_G     1e-10f
#define KSTEPS   12          // 768 / 64
#define MARGIN   1e-3f       // |dlt-thr| below this -> exact fp32 recompute

#define AS3(p) ((__attribute__((address_space(3))) void*)(p))
#define AS1(p) ((const __attribute__((address_space(1))) void*)(p))

typedef __attribute__((ext_vector_type(8))) short bf16x8;   // 8 bf16 = 4 VGPR
typedef __attribute__((ext_vector_type(4))) float f32x4;

// round-to-nearest-even fp32 -> bf16 (bit math, deterministic)
__device__ __forceinline__ unsigned short f2bf(float f) {
  unsigned u = __float_as_uint(f);
  unsigned r = u + 0x7fffu + ((u >> 16) & 1u);
  return (unsigned short)(r >> 16);
}
__device__ __forceinline__ float bf2f(unsigned short h) {
  return __uint_as_float(((unsigned)h) << 16);
}

// ---------------- CSR build ----------------
__global__ void k_deg(const int* __restrict__ ei, int* __restrict__ deg) {
  int e = blockIdx.x * 256 + threadIdx.x;
  if (e >= M_EDGES) return;
  int dst = (e < NEDGE_IN) ? ei[NEDGE_IN + e] : (e - NEDGE_IN);
  atomicAdd(&deg[dst], 1);
}

__global__ void k_scan(const int* __restrict__ deg, int* __restrict__ offs,
                       int* __restrict__ cursor) {
  __shared__ int lds[1024];
  int t = threadIdx.x;
  int4 d = *(const int4*)&deg[t * 4];
  int s = d.x + d.y + d.z + d.w;
  lds[t] = s;
  __syncthreads();
  for (int off = 1; off < 1024; off <<= 1) {
    int v = 0;
    if (t >= off) v = lds[t - off];
    __syncthreads();
    if (t >= off) lds[t] += v;
    __syncthreads();
  }
  int base = lds[t] - s;               // exclusive prefix
  int o0 = base, o1 = o0 + d.x, o2 = o1 + d.y, o3 = o2 + d.z;
  offs[t*4+0] = o0; offs[t*4+1] = o1; offs[t*4+2] = o2; offs[t*4+3] = o3;
  cursor[t*4+0] = o0; cursor[t*4+1] = o1; cursor[t*4+2] = o2; cursor[t*4+3] = o3;
  if (t == 1023) offs[4096] = lds[1023];
}

__global__ void k_scatter(const int* __restrict__ ei, int* __restrict__ cursor,
                          int* __restrict__ srcs) {
  int e = blockIdx.x * 256 + threadIdx.x;
  if (e >= M_EDGES) return;
  int src, dst;
  if (e < NEDGE_IN) { src = ei[e]; dst = ei[NEDGE_IN + e]; }
  else              { src = dst = e - NEDGE_IN; }
  int pos = atomicAdd(&cursor[dst], 1);
  srcs[pos] = src;
}

// ------- W prep: fcW (k-major) -> Wdn (f32 n-major [NPAD][256]),
//   B2p packed bf16 tiles [nt][ks][128][64] pre-swizzled (slot ^= row&7), cdf.
//   K-step order: ks 0..3 = hi, 4..7 = lo, 8..11 = hi  (B' = [hi|lo|hi]) -------
__global__ __launch_bounds__(256) void k_wprep(const float* __restrict__ fcW,
                                               const float* __restrict__ fcb,
                                               float* __restrict__ Wdn,
                                               unsigned short* __restrict__ B2p,
                                               float* __restrict__ cdf) {
  __shared__ float t[64][65];
  int n0 = blockIdx.x * 64;    // 0..8128 step 64
  int k0 = blockIdx.y * 64;    // 0..192  step 64
  for (int i = threadIdx.x; i < 4096; i += 256) {
    int r = i >> 6, c = i & 63;
    int n = n0 + c;
    float d = 0.f;
    if (n < NPAIRS) {
      const float* p = fcW + (size_t)(k0 + r) * (2 * NPAIRS) + 2 * n;
      d = p[0] - p[1];
    }
    t[r][c] = d;
  }
  __syncthreads();
  int ksb = k0 >> 6;           // 0..3
  for (int i = threadIdx.x; i < 4096; i += 256) {
    int rn = i >> 6, ck = i & 63;
    int n = n0 + rn, k = k0 + ck;
    float d = t[ck][rn];
    Wdn[(size_t)n * DIM + k] = d;
    unsigned short hi = f2bf(d);
    unsigned short lo = f2bf(d - bf2f(hi));
    int nt = n >> 7, nn = n & 127;
    int s = ck >> 3, e = ck & 7;
    int ss = s ^ (nn & 7);
    size_t ib = ((size_t)nn << 6) + (ss << 3) + e;
    size_t tb = (size_t)nt * KSTEPS;
    B2p[((tb + ksb)     << 13) + ib] = hi;
    B2p[((tb + 4 + ksb) << 13) + ib] = lo;
    B2p[((tb + 8 + ksb) << 13) + ib] = hi;
  }
  if (k0 == 0 && threadIdx.x < 64) {
    int n = n0 + threadIdx.x;
    if (n < NPAIRS) cdf[n] = fcb[2 * n] - fcb[2 * n + 1];
  }
}

// ---------------- fp32 tiled GEMM: C(Mx256) = A(Mx256) * B(256x256) ----------------
__global__ __launch_bounds__(256) void k_gemm_h(const float* __restrict__ A,
                                                const float* __restrict__ Bm,
                                                float* __restrict__ C) {
  __shared__ float As[16][64];
  __shared__ float Bs[16][64];
  int tid = threadIdx.x;
  int rowBase = blockIdx.x * 64, colBase = blockIdx.y * 64;
  int tx = tid & 15, ty = tid >> 4;
  int ar = tid >> 2, ac = (tid & 3) << 2;
  int bkr = tid >> 6, bcc = tid & 63;
  float acc[4][4] = {{0.f}};
  for (int k0 = 0; k0 < DIM; k0 += 16) {
    float4 av = *(const float4*)&A[(size_t)(rowBase + ar) * DIM + k0 + ac];
    As[ac+0][ar] = av.x; As[ac+1][ar] = av.y; As[ac+2][ar] = av.z; As[ac+3][ar] = av.w;
    #pragma unroll
    for (int j = 0; j < 4; ++j)
      Bs[bkr + 4*j][bcc] = Bm[(size_t)(k0 + bkr + 4*j) * 256 + colBase + bcc];
    __syncthreads();
    #pragma unroll
    for (int kk = 0; kk < 16; ++kk) {
      float4 a4 = *(const float4*)&As[kk][ty << 2];
      float4 b4 = *(const float4*)&Bs[kk][tx << 2];
      float a[4] = {a4.x, a4.y, a4.z, a4.w};
      float b[4] = {b4.x, b4.y, b4.z, b4.w};
      #pragma unroll
      for (int i = 0; i < 4; ++i)
        #pragma unroll
        for (int j = 0; j < 4; ++j) acc[i][j] = fmaf(a[i], b[j], acc[i][j]);
    }
    __syncthreads();
  }
  #pragma unroll
  for (int i = 0; i < 4; ++i) {
    int r = rowBase + (ty << 2) + i;
    #pragma unroll
    for (int j = 0; j < 4; ++j)
      C[(size_t)r * 256 + colBase + (tx << 2) + j] = acc[i][j];
  }
}

// ------- pair GEMM via bf16x3-split MFMA -------
// 128x128 tile, BK=64, double-buffered LDS, 2-phase pipeline, XCD swizzle.
// Epilogue: store dlt+cdf as f32 into full-width Dlt [4096][NPAD].
__global__ __launch_bounds__(256, 2) void k_pairs_mfma(
    const unsigned short* __restrict__ A2p, const unsigned short* __restrict__ B2p,
    const float* __restrict__ cdf, float* __restrict__ Dlt) {
  __shared__ unsigned short As[2][8192];   // 2 x 16 KB
  __shared__ unsigned short Bs[2][8192];   // 2 x 16 KB
  int tid = threadIdx.x;
  int wv = tid >> 6, ln = tid & 63;
  // bijective XCD swizzle: 2048 blocks, 8 XCDs -> 256-block contiguous chunks
  int lin = blockIdx.x + (blockIdx.y << 5);
  int swz = (lin & 7) * 256 + (lin >> 3);
  int mt = swz & 31, nt = swz >> 5;        // mt 0..31, nt 0..63
  int m0 = mt << 7;
  int wm = wv >> 1, wn = wv & 1;           // wave owns 64x64 sub-tile
  int frow = ln & 15, fg = ln >> 4;

  f32x4 zero = {0.f, 0.f, 0.f, 0.f};
  f32x4 acc[4][4];
  #pragma unroll
  for (int i = 0; i < 4; ++i)
    #pragma unroll
    for (int j = 0; j < 4; ++j) acc[i][j] = zero;

  const unsigned short* abase = A2p + (((size_t)mt * KSTEPS) << 13);
  const unsigned short* bbase = B2p + (((size_t)nt * KSTEPS) << 13);

  auto stage = [&](int buf, int ks) {
    const unsigned short* a_ = abase + ((size_t)ks << 13);
    const unsigned short* b_ = bbase + ((size_t)ks << 13);
    #pragma unroll
    for (int q = 0; q < 4; ++q) {
      int off = ((wv * 4 + q) << 9) + (ln << 3);   // ushort units; 16B/lane, linear
      __builtin_amdgcn_global_load_lds(AS1(a_ + off), AS3(&As[buf][off]), 16, 0, 0);
      __builtin_amdgcn_global_load_lds(AS1(b_ + off), AS3(&Bs[buf][off]), 16, 0, 0);
    }
  };

  stage(0, 0);
  __syncthreads();               // implicit vmcnt(0): buf0 ready
  int cur = 0;
  for (int ks = 0; ks < KSTEPS; ++ks) {
    if (ks < KSTEPS - 1) stage(cur ^ 1, ks + 1);   // issue next tile early
    #pragma unroll
    for (int kk2 = 0; kk2 < 2; ++kk2) {
      bf16x8 af[4], bfr[4];
      #pragma unroll
      for (int mi = 0; mi < 4; ++mi) {
        int r = (wm << 6) + (mi << 4) + frow;
        int ss = (kk2 * 4 + fg) ^ (r & 7);         // 2-way bank aliasing (free)
        af[mi] = *(const bf16x8*)&As[cur][(r << 6) + (ss << 3)];
      }
      #pragma unroll
      for (int ni = 0; ni < 4; ++ni) {
        int r = (wn << 6) + (ni << 4) + frow;
        int ss = (kk2 * 4 + fg) ^ (r & 7);
        bfr[ni] = *(const bf16x8*)&Bs[cur][(r << 6) + (ss << 3)];
      }
      #pragma unroll
      for (int mi = 0; mi < 4; ++mi)
        #pragma unroll
        for (int ni = 0; ni < 4; ++ni)
          acc[mi][ni] = __builtin_amdgcn_mfma_f32_16x16x32_bf16(
              af[mi], bfr[ni], acc[mi][ni], 0, 0, 0);
    }
    __syncthreads();             // drains next-tile loads + joins waves
    cur ^= 1;
  }

  // epilogue: D-frag layout col=lane&15, row=(lane>>4)*4+reg (m89-verified).
  // Pure f32 stores of dlt = acc + cdf. Fire-and-forget, coalesced per 16-lane.
  int lr4 = fg << 2;
  #pragma unroll
  for (int ni = 0; ni < 4; ++ni) {
    int cg = (nt << 7) + (wn << 6) + (ni << 4) + frow;    // global pair col
    float cd = (cg < NPAIRS) ? cdf[cg] : 0.f;
    #pragma unroll
    for (int mi = 0; mi < 4; ++mi) {
      #pragma unroll
      for (int jj = 0; jj < 4; ++jj) {
        int r = m0 + (wm << 6) + (mi << 4) + lr4 + jj;
        Dlt[((size_t)r << 13) + cg] = acc[mi][ni][jj] + cd;
      }
    }
  }
}

// ------- fused decide + expand: one block per node row -------
// Phase 1: stream Dlt+gumbel (coalesced float4), decide bits -> LDS byte row.
// Phase 2: write symmetric 128x128 float row (64 KB contiguous) from LDS.
__global__ __launch_bounds__(256) void k_decexp(const float* __restrict__ Dlt,
                                                const float* __restrict__ gumbel,
                                                const float* __restrict__ xf,
                                                const float* __restrict__ Wdn,
                                                const float* __restrict__ cdf,
                                                float* __restrict__ out) {
  __shared__ uint8_t ab[NPAIRS + 64];
  int n = blockIdx.x;
  int tid = threadIdx.x;

  for (int q = tid; q < NPAIRS / 4; q += 256) {
    int c = q << 2;
    float4 d4 = *(const float4*)&Dlt[((size_t)n << 13) + c];
    const float* gp = gumbel + ((size_t)n * NPAIRS + c) * 2;
    float4 g01 = *(const float4*)gp;
    float4 g23 = *(const float4*)(gp + 4);
    float dl[4] = {d4.x, d4.y, d4.z, d4.w};
    float u0[4] = {g01.x, g01.z, g23.x, g23.z};
    float u1[4] = {g01.y, g01.w, g23.y, g23.w};
    uint8_t res[4];
    #pragma unroll
    for (int t = 0; t < 4; ++t) {
      float l0 = EPS_G - __logf(u0[t] + EPS_G);
      float l1 = EPS_G - __logf(u1[t] + EPS_G);
      float thr = __logf(__fdividef(l0, l1));
      float diff = dl[t] - thr;
      uint8_t bit;
      if (__builtin_expect(fabsf(diff) < MARGIN, 0)) {
        // near-threshold: exact fp32 recompute (rare)
        const float4* xr4 = (const float4*)(xf + (size_t)n * DIM);
        const float4* wr4 = (const float4*)(Wdn + (size_t)(c + t) * DIM);
        float dot = 0.f;
        #pragma unroll 16
        for (int k = 0; k < DIM / 4; ++k) {
          float4 a = xr4[k], b = wr4[k];
          dot = fmaf(a.x, b.x, dot); dot = fmaf(a.y, b.y, dot);
          dot = fmaf(a.z, b.z, dot); dot = fmaf(a.w, b.w, dot);
        }
        float l0p = EPS_G - logf(u0[t] + EPS_G);
        float l1p = EPS_G - logf(u1[t] + EPS_G);
        bit = (dot + cdf[c + t] >= logf(l0p / l1p)) ? (uint8_t)1 : (uint8_t)0;
      } else {
        bit = (diff >= 0.f) ? (uint8_t)1 : (uint8_t)0;
      }
      res[t] = bit;
    }
    *(uchar4*)&ab[c] = make_uchar4(res[0], res[1], res[2], res[3]);
  }
  __syncthreads();

  float4* o = (float4*)(out + (size_t)n * 16384);
  for (int q = tid; q < 4096; q += 256) {
    int i = q >> 5;            // row
    int j0 = (q & 31) * 4;
    float v[4];
    #pragma unroll
    for (int j = 0; j < 4; ++j) {
      int jj = j0 + j;
      float x = 0.f;
      if (i < jj)      x = (float)ab[i * (255 - i) / 2 + (jj - i - 1)];
      else if (i > jj) x = (float)ab[jj * (255 - jj) / 2 + (i - jj - 1)];
      v[j] = x;
    }
    o[q] = make_float4(v[0], v[1], v[2], v[3]);
  }
}

// ---------------- per-row attention dots: one wave per node ----------------
__global__ __launch_bounds__(256) void k_rowdot(const float* __restrict__ h,
                                                const float* __restrict__ asrc,
                                                const float* __restrict__ adst,
                                                float* __restrict__ a_s,
                                                float* __restrict__ a_d) {
  int wid = threadIdx.x >> 6, lane = threadIdx.x & 63;
  int n = blockIdx.x * 4 + wid;
  float4 hv = *(const float4*)&h[(size_t)n * DIM + lane * 4];
  float4 s4 = *(const float4*)&asrc[lane * 4];
  float4 d4 = *(const float4*)&adst[lane * 4];
  float vs = hv.x*s4.x + hv.y*s4.y + hv.z*s4.z + hv.w*s4.w;
  float vd = hv.x*d4.x + hv.y*d4.y + hv.z*d4.z + hv.w*d4.w;
  #pragma unroll
  for (int o = 1; o < 64; o <<= 1) {
    vs += __shfl_xor(vs, o, 64);
    vd += __shfl_xor(vd, o, 64);
  }
  if (lane == 0) { a_s[n] = vs; a_d[n] = vd; }
}

// ------- segment softmax + aggregation: one WAVE per dst node -------
// If A2p != nullptr (last layer), also emit bf16x3-split packed A tiles.
__global__ __launch_bounds__(256) void k_agg(const float* __restrict__ h,
                                             const float* __restrict__ a_s,
                                             const float* __restrict__ a_d,
                                             const int* __restrict__ offs,
                                             const int* __restrict__ srcs,
                                             const float* __restrict__ bias,
                                             float* __restrict__ xout,
                                             unsigned short* __restrict__ A2p) {
  int wid  = threadIdx.x >> 6;
  int lane = threadIdx.x & 63;
  int n = blockIdx.x * 4 + wid;
  int beg = offs[n], end = offs[n + 1];
  float ad = a_d[n];

  float m = -3.0e38f;
  for (int i = beg + lane; i < end; i += 64) {
    float e = a_s[srcs[i]] + ad;
    e = (e >= 0.f) ? e : NEG_SLOPE * e;
    m = fmaxf(m, e);
  }
  #pragma unroll
  for (int o = 1; o < 64; o <<= 1) m = fmaxf(m, __shfl_xor(m, o, 64));

  float s = 0.f;
  for (int i = beg + lane; i < end; i += 64) {
    float e = a_s[srcs[i]] + ad;
    e = (e >= 0.f) ? e : NEG_SLOPE * e;
    s += expf(e - m);
  }
  #pragma unroll
  for (int o = 1; o < 64; o <<= 1) s += __shfl_xor(s, o, 64);

  float4 acc = make_float4(0.f, 0.f, 0.f, 0.f);
  for (int base = beg; base < end; base += 64) {
    int cnt = min(64, end - base);
    int mysrc = 0;
    float w = 0.f;
    if (base + lane < end) {
      mysrc = srcs[base + lane];
      float e = a_s[mysrc] + ad;
      e = (e >= 0.f) ? e : NEG_SLOPE * e;
      w = expf(e - m) / s;
    }
    int j = 0;
    for (; j + 4 <= cnt; j += 4) {
      float al0 = __shfl(w, j,     64), al1 = __shfl(w, j + 1, 64);
      float al2 = __shfl(w, j + 2, 64), al3 = __shfl(w, j + 3, 64);
      int   s0  = __shfl(mysrc, j,     64), s1 = __shfl(mysrc, j + 1, 64);
      int   s2  = __shfl(mysrc, j + 2, 64), s3 = __shfl(mysrc, j + 3, 64);
      float4 h0 = *(const float4*)&h[(size_t)s0 * DIM + lane * 4];
      float4 h1 = *(const float4*)&h[(size_t)s1 * DIM + lane * 4];
      float4 h2 = *(const float4*)&h[(size_t)s2 * DIM + lane * 4];
      float4 h3 = *(const float4*)&h[(size_t)s3 * DIM + lane * 4];
      acc.x = fmaf(al0, h0.x, fmaf(al1, h1.x, fmaf(al2, h2.x, fmaf(al3, h3.x, acc.x))));
      acc.y = fmaf(al0, h0.y, fmaf(al1, h1.y, fmaf(al2, h2.y, fmaf(al3, h3.y, acc.y))));
      acc.z = fmaf(al0, h0.z, fmaf(al1, h1.z, fmaf(al2, h2.z, fmaf(al3, h3.z, acc.z))));
      acc.w = fmaf(al0, h0.w, fmaf(al1, h1.w, fmaf(al2, h2.w, fmaf(al3, h3.w, acc.w))));
    }
    for (; j < cnt; ++j) {
      float alpha = __shfl(w, j, 64);
      int   sj    = __shfl(mysrc, j, 64);
      float4 hv = *(const float4*)&h[(size_t)sj * DIM + lane * 4];
      acc.x = fmaf(alpha, hv.x, acc.x);
      acc.y = fmaf(alpha, hv.y, acc.y);
      acc.z = fmaf(alpha, hv.z, acc.z);
      acc.w = fmaf(alpha, hv.w, acc.w);
    }
  }
  float4 bv = *(const float4*)&bias[lane * 4];
  acc.x += bv.x; acc.y += bv.y; acc.z += bv.z; acc.w += bv.w;
  *(float4*)&xout[(size_t)n * DIM + lane * 4] = acc;

  if (A2p) {
    // bf16x3 split of this row, packed pre-swizzled (same layout as k_wprep)
    float vv[4] = {acc.x, acc.y, acc.z, acc.w};
    unsigned short h_[4], l_[4];
    #pragma unroll
    for (int j = 0; j < 4; ++j) {
      h_[j] = f2bf(vv[j]);
      l_[j] = f2bf(vv[j] - bf2f(h_[j]));
    }
    ushort4 hi = make_ushort4(h_[0], h_[1], h_[2], h_[3]);
    ushort4 lo = make_ushort4(l_[0], l_[1], l_[2], l_[3]);
    int k4 = lane << 2;
    int mt = n >> 7, mm = n & 127;
    int kk = k4 & 63;
    int s_ = kk >> 3, e_ = kk & 7;       // e_ in {0,4}
    int ss = s_ ^ (mm & 7);
    size_t ib = ((size_t)mm << 6) + (ss << 3) + e_;
    int ksb = k4 >> 6;
    size_t tb = (size_t)mt * KSTEPS;
    *(ushort4*)&A2p[((tb + ksb)     << 13) + ib] = hi;
    *(ushort4*)&A2p[((tb + 4 + ksb) << 13) + ib] = hi;
    *(ushort4*)&A2p[((tb + 8 + ksb) << 13) + ib] = lo;
  }
}

extern "C" void kernel_launch(void* const* d_in, const int* in_sizes, int n_in,
                              void* d_out, int out_size, void* d_ws, size_t ws_size,
                              hipStream_t stream) {
  const float* x      = (const float*)d_in[0];
  const int*   ei     = (const int*)d_in[1];
  const float* gumbel = (const float*)d_in[2];
  const float* gatW   = (const float*)d_in[3];
  const float* a_src  = (const float*)d_in[4];
  const float* a_dst  = (const float*)d_in[5];
  const float* gatB   = (const float*)d_in[6];
  const float* fcW    = (const float*)d_in[7];
  const float* fcb    = (const float*)d_in[8];
  float* out = (float*)d_out;

  char* ws = (char*)d_ws;
  size_t off = 0;
  auto alloc = [&](size_t bytes) -> void* {
    void* p = ws + off;
    off += (bytes + 255) & ~(size_t)255;
    return p;
  };
  // total ≈ 210 MB
  float* xb0   = (float*)alloc((size_t)NNODES * DIM * 4);
  float* xb1   = (float*)alloc((size_t)NNODES * DIM * 4);
  float* h     = (float*)alloc((size_t)NNODES * DIM * 4);
  float* as_   = (float*)alloc(NNODES * 4);
  float* ad_   = (float*)alloc(NNODES * 4);
  int*   deg   = (int*)alloc(NNODES * 4);
  int*   offs  = (int*)alloc((NNODES + 1) * 4);
  int*   cursor= (int*)alloc(NNODES * 4);
  int*   srcs  = (int*)alloc((size_t)M_EDGES * 4);
  float* Wdn   = (float*)alloc((size_t)NPAD * DIM * 4);            // n-major fp32 fallback
  unsigned short* B2p = (unsigned short*)alloc((size_t)(NPAD/128) * KSTEPS * 8192 * 2);
  unsigned short* A2p = (unsigned short*)alloc((size_t)(NNODES/128) * KSTEPS * 8192 * 2);
  float* cdf   = (float*)alloc(NPAIRS * 4);
  float* Dlt   = (float*)alloc((size_t)NNODES * NPAD * 4);         // 134 MB full-width

  dim3 b256(256);

  hipMemsetAsync(deg, 0, NNODES * 4, stream);
  k_wprep<<<dim3(NPAD / 64, DIM / 64), b256, 0, stream>>>(fcW, fcb, Wdn, B2p, cdf);
  k_deg<<<dim3((M_EDGES + 255) / 256), b256, 0, stream>>>(ei, deg);
  k_scan<<<dim3(1), dim3(1024), 0, stream>>>(deg, offs, cursor);
  k_scatter<<<dim3((M_EDGES + 255) / 256), b256, 0, stream>>>(ei, cursor, srcs);

  const float* xin = x;
  float* bufs[2] = {xb0, xb1};
  for (int l = 0; l < 3; ++l) {
    float* xout = bufs[l & 1];
    k_gemm_h<<<dim3(64, 4), b256, 0, stream>>>(xin, gatW + (size_t)l * DIM * DIM, h);
    k_rowdot<<<dim3(NNODES / 4), b256, 0, stream>>>(h, a_src + (size_t)l * DIM,
                                                    a_dst + (size_t)l * DIM, as_, ad_);
    k_agg<<<dim3(NNODES / 4), b256, 0, stream>>>(h, as_, ad_, offs, srcs,
                                                 gatB + (size_t)l * DIM, xout,
                                                 (l == 2) ? A2p : (unsigned short*)nullptr);
    xin = xout;
  }

  k_pairs_mfma<<<dim3(32, 64), b256, 0, stream>>>(A2p, B2p, cdf, Dlt);
  k_decexp<<<dim3(NNODES), b256, 0, stream>>>(Dlt, gumbel, xin, Wdn, cdf, out);
}